// Round 1
// baseline (175.439 us; speedup 1.0000x reference)
//
#include <hip/hip_runtime.h>
#include <math.h>

#define N_NODES 4096
#define F_IN    512
#define F_OUT   64
#define ALPHA   0.2f

typedef _Float16 half8 __attribute__((ext_vector_type(8)));
typedef float    floatx4 __attribute__((ext_vector_type(4)));

// ---------------- K1: h = x @ W (fp32), hT (f16, t-major), e1 = h @ a1 ----------------
// grid 1024, block 256: 4 rows/block, one wave per row (lane = output col t)
__global__ __launch_bounds__(256) void k_hW(const float* __restrict__ x,
                                            const float* __restrict__ W,
                                            const float* __restrict__ a,
                                            float* __restrict__ h,
                                            _Float16* __restrict__ hT,
                                            float* __restrict__ e1) {
    int tid = threadIdx.x;
    int t = tid & 63;
    int i = blockIdx.x * 4 + (tid >> 6);
    const float* xr = x + (size_t)i * F_IN;
    const float* Wc = W + t;
    float acc = 0.f;
#pragma unroll 4
    for (int k = 0; k < F_IN; k += 4) {
        float4 xv = *(const float4*)(xr + k);
        acc += xv.x * Wc[(k + 0) * F_OUT];
        acc += xv.y * Wc[(k + 1) * F_OUT];
        acc += xv.z * Wc[(k + 2) * F_OUT];
        acc += xv.w * Wc[(k + 3) * F_OUT];
    }
    h[(size_t)i * F_OUT + t] = acc;
    hT[(size_t)t * N_NODES + i] = (_Float16)acc;
    // e1[i] = sum_t h[i,t] * a1[t]
    float v = acc * a[t];
#pragma unroll
    for (int off = 32; off > 0; off >>= 1) v += __shfl_down(v, off, 64);
    if (t == 0) e1[i] = v;
}

// ---------------- K2: Tq[q,t] = sum_r a2[r] h[r*64+q, t];  P[q,j] = f16(exp(lrelu(e1[j]+Tq[q,j&63]))) ----
// grid 64 (one block per q), block 256
__global__ __launch_bounds__(256) void k_P(const float* __restrict__ h,
                                           const float* __restrict__ a,
                                           const float* __restrict__ e1,
                                           _Float16* __restrict__ P) {
    __shared__ float part[4][64];
    __shared__ float Tq[64];
    int q = blockIdx.x;
    int tid = threadIdx.x;
    int t = tid & 63;
    int rp = tid >> 6;
    const float* a2 = a + F_OUT;
    float s = 0.f;
#pragma unroll
    for (int rr = 0; rr < 16; ++rr) {
        int r = rp * 16 + rr;
        s += a2[r] * h[(size_t)(r * 64 + q) * F_OUT + t];
    }
    part[rp][t] = s;
    __syncthreads();
    if (tid < 64) Tq[tid] = part[0][tid] + part[1][tid] + part[2][tid] + part[3][tid];
    __syncthreads();
#pragma unroll
    for (int it = 0; it < 16; ++it) {
        int j = it * 256 + tid;
        float e = e1[j] + Tq[j & 63];
        e = e > 0.f ? e : ALPHA * e;
        P[(size_t)q * N_NODES + j] = (_Float16)__expf(e);
    }
}

// ---------------- K3: out[i,t] = relu( (sum_j adj[i,j]*P[q,j]*h[j,t]) / den[i] ) + bias[t] ----------------
// grid 256 (16 rows per block, one q-group slice), block 256 = 4 waves; wave w owns cols [16w,16w+16)
#define TJ 256
#define AP 264  // padded LDS row (halfs): 264*2=528B = 132 dw -> frag-read conflicts <= cheap

__global__ __launch_bounds__(256) void k_main(const int* __restrict__ adj,
                                              const _Float16* __restrict__ P,
                                              const _Float16* __restrict__ hT,
                                              const float* __restrict__ bias,
                                              float* __restrict__ out) {
    __shared__ _Float16 A_lds[16 * AP];
    __shared__ float den_lds[16];
    int tid  = threadIdx.x;
    int lane = tid & 63;
    int w    = tid >> 6;
    int i0   = blockIdx.x * 16;
    int q    = i0 >> 6;
    int m    = lane & 15;
    int quad = lane >> 4;

    floatx4 acc = {0.f, 0.f, 0.f, 0.f};
    float den = 0.f;
    const _Float16* Bbase = hT + (size_t)(w * 16 + m) * N_NODES;
    const int* adj_base = adj + (size_t)i0 * N_NODES;

    for (int j0 = 0; j0 < N_NODES; j0 += TJ) {
        // ---- stage A tile: A_lds[ii][jj] = adj[i0+ii, j0+jj] ? P[q, j0+jj] : 0  (f16) ----
        _Float16 Pv = P[(size_t)q * N_NODES + j0 + tid];
        const int* arow = adj_base + j0 + tid;
#pragma unroll
        for (int rep = 0; rep < 16; ++rep) {
            int av = arow[(size_t)rep * N_NODES];
            A_lds[rep * AP + tid] = (av > 0) ? Pv : (_Float16)0.f;
        }
        __syncthreads();
        // ---- MFMA over this tile: 8 k-steps of 32 ----
#pragma unroll
        for (int c = 0; c < TJ / 32; ++c) {
            half8 af = *(const half8*)&A_lds[m * AP + c * 32 + quad * 8];
            half8 bf = *(const half8*)(Bbase + j0 + c * 32 + quad * 8);
            acc = __builtin_amdgcn_mfma_f32_16x16x32_f16(af, bf, acc, 0, 0, 0);
            if (w == 0) {
#pragma unroll
                for (int e = 0; e < 8; ++e) den += (float)af[e];
            }
        }
        __syncthreads();
    }
    // den: lane holds partial for row m over its quad's k-stripes; combine quads
    if (w == 0) {
        den += __shfl_xor(den, 16, 64);
        den += __shfl_xor(den, 32, 64);
        if (lane < 16) den_lds[m] = den;
    }
    __syncthreads();
    float b = bias[w * 16 + m];
#pragma unroll
    for (int r = 0; r < 4; ++r) {
        int row = quad * 4 + r;
        float v = acc[r] / den_lds[row];
        v = v > 0.f ? v : 0.f;
        out[(size_t)(i0 + row) * F_OUT + w * 16 + m] = v + b;
    }
}

extern "C" void kernel_launch(void* const* d_in, const int* in_sizes, int n_in,
                              void* d_out, int out_size, void* d_ws, size_t ws_size,
                              hipStream_t stream) {
    const float* x    = (const float*)d_in[0];
    const int*   adj  = (const int*)d_in[1];
    const float* W    = (const float*)d_in[2];
    const float* a    = (const float*)d_in[3];
    const float* bias = (const float*)d_in[4];
    float* out = (float*)d_out;

    char* ws = (char*)d_ws;
    float*    h  = (float*)ws;                                   // 4096*64*4  = 1 MB
    _Float16* hT = (_Float16*)(ws + (1 << 20));                  // 64*4096*2  = 512 KB
    float*    e1 = (float*)(ws + (1 << 20) + (512 << 10));       // 4096*4     = 16 KB
    _Float16* P  = (_Float16*)(ws + (1 << 20) + (528 << 10));    // 64*4096*2  = 512 KB

    k_hW  <<<N_NODES / 4, 256, 0, stream>>>(x, W, a, h, hT, e1);
    k_P   <<<64,          256, 0, stream>>>(h, a, e1, P);
    k_main<<<N_NODES / 16, 256, 0, stream>>>(adj, P, hT, bias, out);
}

// Round 2
// 152.806 us; speedup vs baseline: 1.1481x; 1.1481x over previous
//
#include <hip/hip_runtime.h>
#include <math.h>

#define N_NODES 4096
#define F_IN    512
#define F_OUT   64
#define ALPHA   0.2f

typedef _Float16 half8 __attribute__((ext_vector_type(8)));
typedef _Float16 half4 __attribute__((ext_vector_type(4)));
typedef float    floatx4 __attribute__((ext_vector_type(4)));

// ---------------- k_prep: WT[t][k] = f16(W[k][t])  (64 x 512) ----------------
__global__ __launch_bounds__(256) void k_prep(const float* __restrict__ W,
                                              _Float16* __restrict__ WT) {
    int idx = blockIdx.x * 256 + threadIdx.x;   // 32768 total
    int t = idx >> 9;
    int k = idx & 511;
    WT[idx] = (_Float16)W[k * F_OUT + t];
}

// ---------------- k_hW: h = x@W via MFMA; also hT (f16, t-major) and e1 ----------------
// grid 64 blocks x 256 thr; wave w handles rows i0..i0+15, all 64 cols, K=512
__global__ __launch_bounds__(256) void k_hW(const float* __restrict__ x,
                                            const _Float16* __restrict__ WT,
                                            const float* __restrict__ a,
                                            float* __restrict__ h,
                                            _Float16* __restrict__ hT,
                                            float* __restrict__ e1) {
    int tid  = threadIdx.x;
    int lane = tid & 63;
    int w    = tid >> 6;
    int i0   = (blockIdx.x * 4 + w) * 16;
    int n    = lane & 15;
    int quad = lane >> 4;

    floatx4 acc[4] = {{0,0,0,0},{0,0,0,0},{0,0,0,0},{0,0,0,0}};

    const float* xr = x + (size_t)(i0 + n) * F_IN + quad * 8;
#pragma unroll 4
    for (int kk = 0; kk < F_IN; kk += 32) {
        float4 x0 = *(const float4*)(xr + kk);
        float4 x1 = *(const float4*)(xr + kk + 4);
        half8 af = {(_Float16)x0.x, (_Float16)x0.y, (_Float16)x0.z, (_Float16)x0.w,
                    (_Float16)x1.x, (_Float16)x1.y, (_Float16)x1.z, (_Float16)x1.w};
#pragma unroll
        for (int g = 0; g < 4; ++g) {
            half8 bf = *(const half8*)(WT + (size_t)(g * 16 + n) * F_IN + kk + quad * 8);
            acc[g] = __builtin_amdgcn_mfma_f32_16x16x32_f16(af, bf, acc[g], 0, 0, 0);
        }
    }
    // C layout: row = quad*4 + r, col = g*16 + n
#pragma unroll
    for (int g = 0; g < 4; ++g) {
        half4 hv;
#pragma unroll
        for (int r = 0; r < 4; ++r) {
            h[(size_t)(i0 + quad * 4 + r) * F_OUT + g * 16 + n] = acc[g][r];
            hv[r] = (_Float16)acc[g][r];
        }
        *(half4*)(hT + (size_t)(g * 16 + n) * N_NODES + i0 + quad * 4) = hv;
    }
    // e1[i] = sum_t h[i,t] * a1[t]
    float a1v[4];
#pragma unroll
    for (int g = 0; g < 4; ++g) a1v[g] = a[g * 16 + n];
#pragma unroll
    for (int r = 0; r < 4; ++r) {
        float v = acc[0][r] * a1v[0] + acc[1][r] * a1v[1] + acc[2][r] * a1v[2] + acc[3][r] * a1v[3];
        v += __shfl_xor(v, 1, 64);
        v += __shfl_xor(v, 2, 64);
        v += __shfl_xor(v, 4, 64);
        v += __shfl_xor(v, 8, 64);
        if (n == 0) e1[i0 + quad * 4 + r] = v;
    }
}

// ---------------- k_Tq: Tq[q][t] = sum_r a2[r] * h[r*64+q, t] ----------------
__global__ __launch_bounds__(256) void k_Tq(const float* __restrict__ h,
                                            const float* __restrict__ a,
                                            float* __restrict__ Tq) {
    __shared__ float part[4][64];
    int q = blockIdx.x;
    int tid = threadIdx.x;
    int t = tid & 63;
    int rp = tid >> 6;
    const float* a2 = a + F_OUT;
    float s = 0.f;
#pragma unroll
    for (int rr = 0; rr < 16; ++rr) {
        int r = rp * 16 + rr;
        s += a2[r] * h[(size_t)(r * 64 + q) * F_OUT + t];
    }
    part[rp][t] = s;
    __syncthreads();
    if (tid < 64) Tq[q * 64 + tid] = part[0][tid] + part[1][tid] + part[2][tid] + part[3][tid];
}

// ---------------- k_Pgen: P[q][j] = f16(exp(lrelu(e1[j] + Tq[q][j&63]))) ----------------
__global__ __launch_bounds__(256) void k_Pgen(const float* __restrict__ e1,
                                              const float* __restrict__ Tq,
                                              _Float16* __restrict__ P) {
    int idx = (blockIdx.x * 256 + threadIdx.x) * 4;   // 64*4096 elems
    int q = idx >> 12;
    int j = idx & 4095;
    float4 ev = *(const float4*)(e1 + j);
    float4 tv = *(const float4*)(Tq + q * 64 + (j & 63));
    float e[4] = {ev.x + tv.x, ev.y + tv.y, ev.z + tv.z, ev.w + tv.w};
    half4 pv;
#pragma unroll
    for (int r = 0; r < 4; ++r) {
        float x = e[r] > 0.f ? e[r] : ALPHA * e[r];
        pv[r] = (_Float16)__expf(x);
    }
    *(half4*)(P + idx) = pv;
}

// ---------------- k_main: barrier-free MFMA, atomic partials ----------------
// 4096 waves: wave = (row-group g of 16 rows) x (j-chunk s of 256 cols)
__global__ __launch_bounds__(256) void k_main(const int* __restrict__ adj,
                                              const _Float16* __restrict__ P,
                                              const _Float16* __restrict__ hT,
                                              float* __restrict__ out_pre,
                                              float* __restrict__ den) {
    int tid  = threadIdx.x;
    int lane = tid & 63;
    int w    = tid >> 6;
    int waveId = blockIdx.x * 4 + w;      // 0..4095
    int g   = waveId >> 4;                 // row-group
    int s   = waveId & 15;                 // j-chunk
    int i0  = g * 16;
    int q   = i0 >> 6;
    int n    = lane & 15;
    int quad = lane >> 4;
    int jbase = s * 256 + quad * 8;

    floatx4 acc[4] = {{0,0,0,0},{0,0,0,0},{0,0,0,0},{0,0,0,0}};
    floatx4 accd = {0, 0, 0, 0};
    // ones-column B fragment: col n==0 gets 1.0 -> accd col0 = row sums of A
    _Float16 one_h = (n == 0) ? (_Float16)1.0f : (_Float16)0.0f;
    half8 ones_f = {one_h, one_h, one_h, one_h, one_h, one_h, one_h, one_h};

    const int*      arow = adj + (size_t)(i0 + n) * N_NODES + jbase;
    const _Float16* prow = P + (size_t)q * N_NODES + jbase;
    const _Float16* hrow = hT + (size_t)n * N_NODES + jbase;

#pragma unroll
    for (int c = 0; c < 8; ++c) {
        int joff = c * 32;
        int4 a0 = *(const int4*)(arow + joff);
        int4 a1v = *(const int4*)(arow + joff + 4);
        half8 pv = *(const half8*)(prow + joff);
        half8 af;
        af[0] = a0.x  > 0 ? pv[0] : (_Float16)0.f;
        af[1] = a0.y  > 0 ? pv[1] : (_Float16)0.f;
        af[2] = a0.z  > 0 ? pv[2] : (_Float16)0.f;
        af[3] = a0.w  > 0 ? pv[3] : (_Float16)0.f;
        af[4] = a1v.x > 0 ? pv[4] : (_Float16)0.f;
        af[5] = a1v.y > 0 ? pv[5] : (_Float16)0.f;
        af[6] = a1v.z > 0 ? pv[6] : (_Float16)0.f;
        af[7] = a1v.w > 0 ? pv[7] : (_Float16)0.f;
#pragma unroll
        for (int g4 = 0; g4 < 4; ++g4) {
            half8 bf = *(const half8*)(hrow + (size_t)g4 * 16 * N_NODES + joff);
            acc[g4] = __builtin_amdgcn_mfma_f32_16x16x32_f16(af, bf, acc[g4], 0, 0, 0);
        }
        accd = __builtin_amdgcn_mfma_f32_16x16x32_f16(af, ones_f, accd, 0, 0, 0);
    }
    // scatter partials: C row = quad*4+r, col = g4*16+n
#pragma unroll
    for (int g4 = 0; g4 < 4; ++g4)
#pragma unroll
        for (int r = 0; r < 4; ++r)
            atomicAdd(&out_pre[(size_t)(i0 + quad * 4 + r) * F_OUT + g4 * 16 + n], acc[g4][r]);
    if (n == 0) {
#pragma unroll
        for (int r = 0; r < 4; ++r)
            atomicAdd(&den[i0 + quad * 4 + r], accd[r]);
    }
}

// ---------------- k_out: out = relu(out_pre/den) + bias ----------------
__global__ __launch_bounds__(256) void k_out(const float* __restrict__ out_pre,
                                             const float* __restrict__ den,
                                             const float* __restrict__ bias,
                                             float* __restrict__ out) {
    int idx = blockIdx.x * 256 + threadIdx.x;   // 262144
    int i = idx >> 6;
    int t = idx & 63;
    float v = out_pre[idx] / den[i];
    v = v > 0.f ? v : 0.f;
    out[idx] = v + bias[t];
}

extern "C" void kernel_launch(void* const* d_in, const int* in_sizes, int n_in,
                              void* d_out, int out_size, void* d_ws, size_t ws_size,
                              hipStream_t stream) {
    const float* x    = (const float*)d_in[0];
    const int*   adj  = (const int*)d_in[1];
    const float* W    = (const float*)d_in[2];
    const float* a    = (const float*)d_in[3];
    const float* bias = (const float*)d_in[4];
    float* out = (float*)d_out;

    char* ws = (char*)d_ws;
    // layout (aliasing: out_pre reuses h after k_Tq; den reuses e1 after k_Pgen)
    float*    h       = (float*)ws;                           // 1 MB   (also out_pre)
    _Float16* hT      = (_Float16*)(ws + (1 << 20));          // 512 KB
    float*    e1      = (float*)(ws + 1536 * 1024);           // 16 KB  (also den)
    _Float16* P       = (_Float16*)(ws + 1552 * 1024);        // 512 KB
    _Float16* WT      = (_Float16*)(ws + 2064 * 1024);        // 64 KB
    float*    Tq      = (float*)(ws + 2128 * 1024);           // 16 KB
    float*    out_pre = h;
    float*    den     = e1;

    k_prep<<<128, 256, 0, stream>>>(W, WT);
    k_hW  <<<64, 256, 0, stream>>>(x, WT, a, h, hT, e1);
    k_Tq  <<<64, 256, 0, stream>>>(h, a, Tq);
    k_Pgen<<<256, 256, 0, stream>>>(e1, Tq, P);
    hipMemsetAsync(out_pre, 0, N_NODES * F_OUT * sizeof(float), stream);
    hipMemsetAsync(den, 0, N_NODES * sizeof(float), stream);
    k_main<<<1024, 256, 0, stream>>>(adj, P, hT, out_pre, den);
    k_out <<<1024, 256, 0, stream>>>(out_pre, den, bias, out);
}

// Round 3
// 141.723 us; speedup vs baseline: 1.2379x; 1.0782x over previous
//
#include <hip/hip_runtime.h>
#include <math.h>

#define N_NODES 4096
#define F_IN    512
#define F_OUT   64
#define ALPHA   0.2f

typedef _Float16 half8 __attribute__((ext_vector_type(8)));
typedef _Float16 half4 __attribute__((ext_vector_type(4)));
typedef float    floatx4 __attribute__((ext_vector_type(4)));

// ---------------- k_prep: WT[t][k] = f16(W[k][t])  (64 x 512) ----------------
__global__ __launch_bounds__(256) void k_prep(const float* __restrict__ W,
                                              _Float16* __restrict__ WT) {
    int idx = blockIdx.x * 256 + threadIdx.x;   // 32768 total
    int t = idx >> 9;
    int k = idx & 511;
    WT[idx] = (_Float16)W[k * F_OUT + t];
}

// ---------------- k_hW: h = x@W via MFMA (K-split across 4 waves); h, hT(f16), e1 ----------------
// grid 256 blocks x 256 thr; block b -> rows b*16..b*16+15; wave w -> K slice [w*128, w*128+128)
__global__ __launch_bounds__(256) void k_hW(const float* __restrict__ x,
                                            const _Float16* __restrict__ WT,
                                            const float* __restrict__ a,
                                            float* __restrict__ h,
                                            _Float16* __restrict__ hT,
                                            float* __restrict__ e1) {
    __shared__ float red[4][16][64];   // [wave][g4*4+r][lane]
    int tid  = threadIdx.x;
    int lane = tid & 63;
    int w    = tid >> 6;
    int i0   = blockIdx.x * 16;
    int n    = lane & 15;
    int quad = lane >> 4;

    floatx4 acc[4] = {{0,0,0,0},{0,0,0,0},{0,0,0,0},{0,0,0,0}};

    const float* xr = x + (size_t)(i0 + n) * F_IN + w * 128 + quad * 8;
    const _Float16* wb = WT + w * 128 + quad * 8;
#pragma unroll
    for (int kk = 0; kk < 128; kk += 32) {
        float4 x0 = *(const float4*)(xr + kk);
        float4 x1 = *(const float4*)(xr + kk + 4);
        half8 af = {(_Float16)x0.x, (_Float16)x0.y, (_Float16)x0.z, (_Float16)x0.w,
                    (_Float16)x1.x, (_Float16)x1.y, (_Float16)x1.z, (_Float16)x1.w};
#pragma unroll
        for (int g = 0; g < 4; ++g) {
            half8 bf = *(const half8*)(wb + (size_t)(g * 16 + n) * F_IN + kk);
            acc[g] = __builtin_amdgcn_mfma_f32_16x16x32_f16(af, bf, acc[g], 0, 0, 0);
        }
    }
#pragma unroll
    for (int g = 0; g < 4; ++g)
#pragma unroll
        for (int r = 0; r < 4; ++r)
            red[w][g * 4 + r][lane] = acc[g][r];
    __syncthreads();
    if (w != 0) return;
#pragma unroll
    for (int g = 0; g < 4; ++g)
#pragma unroll
        for (int r = 0; r < 4; ++r)
            acc[g][r] = red[0][g * 4 + r][lane] + red[1][g * 4 + r][lane] +
                        red[2][g * 4 + r][lane] + red[3][g * 4 + r][lane];
    // C layout: row = quad*4 + r, col = g*16 + n
#pragma unroll
    for (int g = 0; g < 4; ++g) {
        half4 hv;
#pragma unroll
        for (int r = 0; r < 4; ++r) {
            h[(size_t)(i0 + quad * 4 + r) * F_OUT + g * 16 + n] = acc[g][r];
            hv[r] = (_Float16)acc[g][r];
        }
        *(half4*)(hT + (size_t)(g * 16 + n) * N_NODES + i0 + quad * 4) = hv;
    }
    float a1v[4];
#pragma unroll
    for (int g = 0; g < 4; ++g) a1v[g] = a[g * 16 + n];
#pragma unroll
    for (int r = 0; r < 4; ++r) {
        float v = acc[0][r] * a1v[0] + acc[1][r] * a1v[1] + acc[2][r] * a1v[2] + acc[3][r] * a1v[3];
        v += __shfl_xor(v, 1, 64);
        v += __shfl_xor(v, 2, 64);
        v += __shfl_xor(v, 4, 64);
        v += __shfl_xor(v, 8, 64);
        if (n == 0) e1[i0 + quad * 4 + r] = v;
    }
}

// ---------------- k_TqP: Tq (LDS) -> P[q][j] = f16(exp(lrelu(e1[j]+Tq[j&63]))); also zero out_pre/den ----
// grid 64 blocks (one per q) x 256
__global__ __launch_bounds__(256) void k_TqP(const float* __restrict__ h,
                                             const float* __restrict__ a,
                                             const float* __restrict__ e1,
                                             _Float16* __restrict__ P,
                                             float* __restrict__ out_pre,
                                             float* __restrict__ den) {
    __shared__ float part[4][64];
    __shared__ float TqS[64];
    int q = blockIdx.x;
    int tid = threadIdx.x;
    int t = tid & 63;
    int rp = tid >> 6;
    const float* a2 = a + F_OUT;
    float s = 0.f;
#pragma unroll
    for (int rr = 0; rr < 16; ++rr) {
        int r = rp * 16 + rr;
        s += a2[r] * h[(size_t)(r * 64 + q) * F_OUT + t];
    }
    part[rp][t] = s;
    // zero-fill out_pre (64 blk * 256 thr * 4 it * float4 = 262144 floats) and den
    float4 z = {0.f, 0.f, 0.f, 0.f};
#pragma unroll
    for (int it = 0; it < 4; ++it)
        ((float4*)out_pre)[(it * 64 + q) * 256 + tid] = z;
    if (tid < 16) ((float4*)den)[q * 16 + tid] = z;
    __syncthreads();
    if (tid < 64) TqS[tid] = part[0][tid] + part[1][tid] + part[2][tid] + part[3][tid];
    __syncthreads();
#pragma unroll
    for (int it = 0; it < 4; ++it) {
        int j = (it * 256 + tid) * 4;
        float4 ev = *(const float4*)(e1 + j);
        float4 tv = *(const float4*)(TqS + (j & 63));
        float e[4] = {ev.x + tv.x, ev.y + tv.y, ev.z + tv.z, ev.w + tv.w};
        half4 pv;
#pragma unroll
        for (int r = 0; r < 4; ++r) {
            float xx = e[r] > 0.f ? e[r] : ALPHA * e[r];
            pv[r] = (_Float16)__expf(xx);
        }
        *(half4*)(P + (size_t)q * N_NODES + j) = pv;
    }
}

// ---------------- k_main: barrier-free MFMA, full adj-tile register preload ----------------
// 4096 waves: wave = (row-group g of 16 rows) x (j-chunk s of 256 cols)
__global__ __launch_bounds__(256, 4) void k_main(const int* __restrict__ adj,
                                                 const _Float16* __restrict__ P,
                                                 const _Float16* __restrict__ hT,
                                                 float* __restrict__ out_pre,
                                                 float* __restrict__ den) {
    int tid  = threadIdx.x;
    int lane = tid & 63;
    int w    = tid >> 6;
    int waveId = blockIdx.x * 4 + w;      // 0..4095
    int g   = waveId >> 4;                 // row-group
    int s   = waveId & 15;                 // j-chunk
    int i0  = g * 16;
    int q   = i0 >> 6;
    int n    = lane & 15;
    int quad = lane >> 4;
    int jbase = s * 256 + quad * 8;

    const int*      arow = adj + (size_t)(i0 + n) * N_NODES + jbase;
    const _Float16* prow = P + (size_t)q * N_NODES + jbase;
    const _Float16* hrow = hT + (size_t)n * N_NODES + jbase;

    // preload the wave's whole adj tile: 16 dwordx4 in flight
    int4 abuf[16];
#pragma unroll
    for (int c = 0; c < 8; ++c) {
        abuf[2 * c]     = *(const int4*)(arow + c * 32);
        abuf[2 * c + 1] = *(const int4*)(arow + c * 32 + 4);
    }

    floatx4 acc[4] = {{0,0,0,0},{0,0,0,0},{0,0,0,0},{0,0,0,0}};
    floatx4 accd = {0, 0, 0, 0};
    _Float16 one_h = (n == 0) ? (_Float16)1.0f : (_Float16)0.0f;
    half8 ones_f = {one_h, one_h, one_h, one_h, one_h, one_h, one_h, one_h};

#pragma unroll
    for (int c = 0; c < 8; ++c) {
        int joff = c * 32;
        int4 a0 = abuf[2 * c];
        int4 a1v = abuf[2 * c + 1];
        half8 pv = *(const half8*)(prow + joff);
        half8 af;
        af[0] = a0.x  > 0 ? pv[0] : (_Float16)0.f;
        af[1] = a0.y  > 0 ? pv[1] : (_Float16)0.f;
        af[2] = a0.z  > 0 ? pv[2] : (_Float16)0.f;
        af[3] = a0.w  > 0 ? pv[3] : (_Float16)0.f;
        af[4] = a1v.x > 0 ? pv[4] : (_Float16)0.f;
        af[5] = a1v.y > 0 ? pv[5] : (_Float16)0.f;
        af[6] = a1v.z > 0 ? pv[6] : (_Float16)0.f;
        af[7] = a1v.w > 0 ? pv[7] : (_Float16)0.f;
#pragma unroll
        for (int g4 = 0; g4 < 4; ++g4) {
            half8 bf = *(const half8*)(hrow + (size_t)g4 * 16 * N_NODES + joff);
            acc[g4] = __builtin_amdgcn_mfma_f32_16x16x32_f16(af, bf, acc[g4], 0, 0, 0);
        }
        accd = __builtin_amdgcn_mfma_f32_16x16x32_f16(af, ones_f, accd, 0, 0, 0);
    }
    // scatter partials, rotated by s to spread cacheline contention
#pragma unroll
    for (int gg = 0; gg < 4; ++gg) {
        int g4 = (gg + s) & 3;
#pragma unroll
        for (int rr = 0; rr < 4; ++rr) {
            int r = (rr + (s >> 2)) & 3;
            atomicAdd(&out_pre[(size_t)(i0 + quad * 4 + r) * F_OUT + g4 * 16 + n], acc[g4][r]);
        }
    }
    if (n == 0) {
#pragma unroll
        for (int r = 0; r < 4; ++r)
            atomicAdd(&den[i0 + quad * 4 + r], accd[r]);
    }
}

// ---------------- k_out: out = relu(out_pre/den) + bias ----------------
__global__ __launch_bounds__(256) void k_out(const float* __restrict__ out_pre,
                                             const float* __restrict__ den,
                                             const float* __restrict__ bias,
                                             float* __restrict__ out) {
    int idx = blockIdx.x * 256 + threadIdx.x;   // 262144
    int i = idx >> 6;
    int t = idx & 63;
    float v = out_pre[idx] / den[i];
    v = v > 0.f ? v : 0.f;
    out[idx] = v + bias[t];
}

extern "C" void kernel_launch(void* const* d_in, const int* in_sizes, int n_in,
                              void* d_out, int out_size, void* d_ws, size_t ws_size,
                              hipStream_t stream) {
    const float* x    = (const float*)d_in[0];
    const int*   adj  = (const int*)d_in[1];
    const float* W    = (const float*)d_in[2];
    const float* a    = (const float*)d_in[3];
    const float* bias = (const float*)d_in[4];
    float* out = (float*)d_out;

    char* ws = (char*)d_ws;
    float*    h       = (float*)ws;                           // 1 MB
    _Float16* hT      = (_Float16*)(ws + 1024 * 1024);        // 512 KB
    float*    e1      = (float*)(ws + 1536 * 1024);           // 16 KB
    _Float16* P       = (_Float16*)(ws + 1552 * 1024);        // 512 KB
    _Float16* WT      = (_Float16*)(ws + 2064 * 1024);        // 64 KB
    float*    out_pre = (float*)(ws + 2128 * 1024);           // 1 MB
    float*    den     = (float*)(ws + 3152 * 1024);           // 16 KB

    k_prep<<<128, 256, 0, stream>>>(W, WT);
    k_hW  <<<256, 256, 0, stream>>>(x, WT, a, h, hT, e1);
    k_TqP <<<64, 256, 0, stream>>>(h, a, e1, P, out_pre, den);
    k_main<<<1024, 256, 0, stream>>>(adj, P, hT, out_pre, den);
    k_out <<<1024, 256, 0, stream>>>(out_pre, den, bias, out);
}

// Round 4
// 139.085 us; speedup vs baseline: 1.2614x; 1.0190x over previous
//
#include <hip/hip_runtime.h>
#include <math.h>

#define N_NODES 4096
#define F_IN    512
#define F_OUT   64
#define ALPHA   0.2f
#define NPART   16

typedef _Float16 half8 __attribute__((ext_vector_type(8)));
typedef _Float16 half4 __attribute__((ext_vector_type(4)));
typedef float    floatx4 __attribute__((ext_vector_type(4)));

// ---------------- k_prep: WT[t][k] = f16(W[k][t])  (64 x 512) ----------------
__global__ __launch_bounds__(256) void k_prep(const float* __restrict__ W,
                                              _Float16* __restrict__ WT) {
    int idx = blockIdx.x * 256 + threadIdx.x;   // 32768 total
    int t = idx >> 9;
    int k = idx & 511;
    WT[idx] = (_Float16)W[k * F_OUT + t];
}

// ---------------- k_hW: h = x@W via MFMA (K-split across 4 waves); h, hT(f16), e1 ----------------
__global__ __launch_bounds__(256) void k_hW(const float* __restrict__ x,
                                            const _Float16* __restrict__ WT,
                                            const float* __restrict__ a,
                                            float* __restrict__ h,
                                            _Float16* __restrict__ hT,
                                            float* __restrict__ e1) {
    __shared__ float red[4][16][64];   // [wave][g4*4+r][lane]
    int tid  = threadIdx.x;
    int lane = tid & 63;
    int w    = tid >> 6;
    int i0   = blockIdx.x * 16;
    int n    = lane & 15;
    int quad = lane >> 4;

    floatx4 acc[4] = {{0,0,0,0},{0,0,0,0},{0,0,0,0},{0,0,0,0}};

    const float* xr = x + (size_t)(i0 + n) * F_IN + w * 128 + quad * 8;
    const _Float16* wb = WT + w * 128 + quad * 8;
#pragma unroll
    for (int kk = 0; kk < 128; kk += 32) {
        float4 x0 = *(const float4*)(xr + kk);
        float4 x1 = *(const float4*)(xr + kk + 4);
        half8 af = {(_Float16)x0.x, (_Float16)x0.y, (_Float16)x0.z, (_Float16)x0.w,
                    (_Float16)x1.x, (_Float16)x1.y, (_Float16)x1.z, (_Float16)x1.w};
#pragma unroll
        for (int g = 0; g < 4; ++g) {
            half8 bf = *(const half8*)(wb + (size_t)(g * 16 + n) * F_IN + kk);
            acc[g] = __builtin_amdgcn_mfma_f32_16x16x32_f16(af, bf, acc[g], 0, 0, 0);
        }
    }
#pragma unroll
    for (int g = 0; g < 4; ++g)
#pragma unroll
        for (int r = 0; r < 4; ++r)
            red[w][g * 4 + r][lane] = acc[g][r];
    __syncthreads();
    if (w != 0) return;
#pragma unroll
    for (int g = 0; g < 4; ++g)
#pragma unroll
        for (int r = 0; r < 4; ++r)
            acc[g][r] = red[0][g * 4 + r][lane] + red[1][g * 4 + r][lane] +
                        red[2][g * 4 + r][lane] + red[3][g * 4 + r][lane];
#pragma unroll
    for (int g = 0; g < 4; ++g) {
        half4 hv;
#pragma unroll
        for (int r = 0; r < 4; ++r) {
            h[(size_t)(i0 + quad * 4 + r) * F_OUT + g * 16 + n] = acc[g][r];
            hv[r] = (_Float16)acc[g][r];
        }
        *(half4*)(hT + (size_t)(g * 16 + n) * N_NODES + i0 + quad * 4) = hv;
    }
    float a1v[4];
#pragma unroll
    for (int g = 0; g < 4; ++g) a1v[g] = a[g * 16 + n];
#pragma unroll
    for (int r = 0; r < 4; ++r) {
        float v = acc[0][r] * a1v[0] + acc[1][r] * a1v[1] + acc[2][r] * a1v[2] + acc[3][r] * a1v[3];
        v += __shfl_xor(v, 1, 64);
        v += __shfl_xor(v, 2, 64);
        v += __shfl_xor(v, 4, 64);
        v += __shfl_xor(v, 8, 64);
        if (n == 0) e1[i0 + quad * 4 + r] = v;
    }
}

// ---------------- k_TqP: Tq (LDS) -> P[q][j] = f16(exp(lrelu(e1[j]+Tq[j&63]))) ----------------
__global__ __launch_bounds__(256) void k_TqP(const float* __restrict__ h,
                                             const float* __restrict__ a,
                                             const float* __restrict__ e1,
                                             _Float16* __restrict__ P) {
    __shared__ float part[4][64];
    __shared__ float TqS[64];
    int q = blockIdx.x;
    int tid = threadIdx.x;
    int t = tid & 63;
    int rp = tid >> 6;
    const float* a2 = a + F_OUT;
    float s = 0.f;
#pragma unroll
    for (int rr = 0; rr < 16; ++rr) {
        int r = rp * 16 + rr;
        s += a2[r] * h[(size_t)(r * 64 + q) * F_OUT + t];
    }
    part[rp][t] = s;
    __syncthreads();
    if (tid < 64) TqS[tid] = part[0][tid] + part[1][tid] + part[2][tid] + part[3][tid];
    __syncthreads();
#pragma unroll
    for (int it = 0; it < 4; ++it) {
        int j = (it * 256 + tid) * 4;
        float4 ev = *(const float4*)(e1 + j);
        float4 tv = *(const float4*)(TqS + (j & 63));
        float e[4] = {ev.x + tv.x, ev.y + tv.y, ev.z + tv.z, ev.w + tv.w};
        half4 pv;
#pragma unroll
        for (int r = 0; r < 4; ++r) {
            float xx = e[r] > 0.f ? e[r] : ALPHA * e[r];
            pv[r] = (_Float16)__expf(xx);
        }
        *(half4*)(P + (size_t)q * N_NODES + j) = pv;
    }
}

// ---------------- k_main: barrier-free MFMA, NO atomics — private partials per j-chunk ----------------
// 4096 waves: wave = (row-group g of 16 rows) x (j-chunk s of 256 cols)
__global__ __launch_bounds__(256, 4) void k_main(const int* __restrict__ adj,
                                                 const _Float16* __restrict__ P,
                                                 const _Float16* __restrict__ hT,
                                                 float* __restrict__ out_part,
                                                 float* __restrict__ den_part) {
    int tid  = threadIdx.x;
    int lane = tid & 63;
    int w    = tid >> 6;
    int waveId = blockIdx.x * 4 + w;      // 0..4095
    int g   = waveId >> 4;                 // row-group
    int s   = waveId & 15;                 // j-chunk
    int i0  = g * 16;
    int q   = i0 >> 6;
    int n    = lane & 15;
    int quad = lane >> 4;
    int jbase = s * 256 + quad * 8;

    const int*      arow = adj + (size_t)(i0 + n) * N_NODES + jbase;
    const _Float16* prow = P + (size_t)q * N_NODES + jbase;
    const _Float16* hrow = hT + (size_t)n * N_NODES + jbase;

    // preload the wave's whole adj tile: 16 dwordx4 in flight, pinned by sched_barrier
    int4 abuf[16];
#pragma unroll
    for (int c = 0; c < 8; ++c) {
        abuf[2 * c]     = *(const int4*)(arow + c * 32);
        abuf[2 * c + 1] = *(const int4*)(arow + c * 32 + 4);
    }
    __builtin_amdgcn_sched_barrier(0);

    floatx4 acc[4] = {{0,0,0,0},{0,0,0,0},{0,0,0,0},{0,0,0,0}};
    floatx4 accd = {0, 0, 0, 0};
    _Float16 one_h = (n == 0) ? (_Float16)1.0f : (_Float16)0.0f;
    half8 ones_f = {one_h, one_h, one_h, one_h, one_h, one_h, one_h, one_h};

#pragma unroll
    for (int c = 0; c < 8; ++c) {
        int joff = c * 32;
        int4 a0 = abuf[2 * c];
        int4 a1v = abuf[2 * c + 1];
        half8 pv = *(const half8*)(prow + joff);
        half8 af;
        af[0] = a0.x  > 0 ? pv[0] : (_Float16)0.f;
        af[1] = a0.y  > 0 ? pv[1] : (_Float16)0.f;
        af[2] = a0.z  > 0 ? pv[2] : (_Float16)0.f;
        af[3] = a0.w  > 0 ? pv[3] : (_Float16)0.f;
        af[4] = a1v.x > 0 ? pv[4] : (_Float16)0.f;
        af[5] = a1v.y > 0 ? pv[5] : (_Float16)0.f;
        af[6] = a1v.z > 0 ? pv[6] : (_Float16)0.f;
        af[7] = a1v.w > 0 ? pv[7] : (_Float16)0.f;
#pragma unroll
        for (int g4 = 0; g4 < 4; ++g4) {
            half8 bf = *(const half8*)(hrow + (size_t)g4 * 16 * N_NODES + joff);
            acc[g4] = __builtin_amdgcn_mfma_f32_16x16x32_f16(af, bf, acc[g4], 0, 0, 0);
        }
        accd = __builtin_amdgcn_mfma_f32_16x16x32_f16(af, ones_f, accd, 0, 0, 0);
    }
    // plain stores to this chunk's private partial
    float* op = out_part + ((size_t)s * N_NODES + i0) * F_OUT;
#pragma unroll
    for (int g4 = 0; g4 < 4; ++g4)
#pragma unroll
        for (int r = 0; r < 4; ++r)
            op[(quad * 4 + r) * F_OUT + g4 * 16 + n] = acc[g4][r];
    if (n == 0) {
#pragma unroll
        for (int r = 0; r < 4; ++r)
            den_part[s * N_NODES + i0 + quad * 4 + r] = accd[r];
    }
}

// ---------------- k_out: out = relu(sum_s out_part / sum_s den_part) + bias ----------------
__global__ __launch_bounds__(256) void k_out(const float* __restrict__ out_part,
                                             const float* __restrict__ den_part,
                                             const float* __restrict__ bias,
                                             float* __restrict__ out) {
    int idx = blockIdx.x * 256 + threadIdx.x;   // 262144
    int i = idx >> 6;
    int t = idx & 63;
    float sacc = 0.f, dacc = 0.f;
#pragma unroll
    for (int p = 0; p < NPART; ++p)
        sacc += out_part[(size_t)p * N_NODES * F_OUT + idx];
#pragma unroll
    for (int p = 0; p < NPART; ++p)
        dacc += den_part[p * N_NODES + i];
    float v = sacc / dacc;
    v = v > 0.f ? v : 0.f;
    out[idx] = v + bias[t];
}

extern "C" void kernel_launch(void* const* d_in, const int* in_sizes, int n_in,
                              void* d_out, int out_size, void* d_ws, size_t ws_size,
                              hipStream_t stream) {
    const float* x    = (const float*)d_in[0];
    const int*   adj  = (const int*)d_in[1];
    const float* W    = (const float*)d_in[2];
    const float* a    = (const float*)d_in[3];
    const float* bias = (const float*)d_in[4];
    float* out = (float*)d_out;

    char* ws = (char*)d_ws;
    float*    h        = (float*)ws;                            // 1 MB
    _Float16* hT       = (_Float16*)(ws + 1024 * 1024);         // 512 KB
    float*    e1       = (float*)(ws + 1536 * 1024);            // 16 KB
    _Float16* P        = (_Float16*)(ws + 1552 * 1024);         // 512 KB
    _Float16* WT       = (_Float16*)(ws + 2064 * 1024);         // 64 KB
    float*    out_part = (float*)(ws + 2128 * 1024);            // 16 MB
    float*    den_part = (float*)(ws + (2128 + 16384) * 1024);  // 256 KB

    k_prep<<<128, 256, 0, stream>>>(W, WT);
    k_hW  <<<256, 256, 0, stream>>>(x, WT, a, h, hT, e1);
    k_TqP <<<64, 256, 0, stream>>>(h, a, e1, P);
    k_main<<<1024, 256, 0, stream>>>(adj, P, hT, out_part, den_part);
    k_out <<<1024, 256, 0, stream>>>(out_part, den_part, bias, out);
}